// Round 8
// baseline (307.966 us; speedup 1.0000x reference)
//
#include <hip/hip_runtime.h>
#include <hip/hip_bf16.h>
#include <stdint.h>
#include <stddef.h>

#define NEG_SLOPE 0.2f
#define XS 136   // padded LDS row stride in bf16 elems (272 B, 16B-aligned, kills 256B bank alias)

// CSR bucket build: bucket = dst >> 9 (512 nodes/bucket), 196 buckets for N=100k.
#define NBK   196
#define BWSH  9
#define BCAP  12288
#define NPREP 64   // prep blocks appended after scatter blocks

typedef __bf16 bf16x8 __attribute__((ext_vector_type(8)));
typedef float  f32x4  __attribute__((ext_vector_type(4)));

__device__ __forceinline__ float bf2f(__hip_bfloat16 b){ return __bfloat162float(b); }
__device__ __forceinline__ float lo_bf(unsigned u){ return __uint_as_float(u << 16); }
__device__ __forceinline__ float hi_bf(unsigned u){ return __uint_as_float(u & 0xffff0000u); }
__device__ __forceinline__ float lrelu(float u){ return fmaxf(u, NEG_SLOPE * u); }
__device__ __forceinline__ unsigned short f2bf(float f){           // RNE bf16
    unsigned u = __float_as_uint(f);
    return (unsigned short)((u + 0x7fffu + ((u >> 16) & 1u)) >> 16);
}
__device__ __forceinline__ float bfs2f(unsigned short s){ return __uint_as_float((unsigned)s << 16); }
__device__ __forceinline__ float ldraw(const void* p, int i, int isf){
    return isf ? ((const float*)p)[i] : bf2f(((const __hip_bfloat16*)p)[i]);
}

// ---------------------------------------------------------------- detect (1 block)
// flags[0]: 1 if edge_index is int64; flags[1]: 1 if floats are fp32.
// gcur zeroed (holds per-bucket COUNTS).
__global__ void detect_kernel(const unsigned* __restrict__ ei,
                              const unsigned* __restrict__ xw,
                              int* __restrict__ flags,
                              int* __restrict__ gcur){
    __shared__ int vote;
    const int t = threadIdx.x;
    if (t == 0) vote = 0;
    if (t < NBK) gcur[t] = 0;
    __syncthreads();
    if (t < 64){
        unsigned long long m = __ballot(ei[2*t + 1] != 0u);
        if (t == 0) flags[0] = (m == 0ull) ? 1 : 0;
    }
    {
        unsigned lo = xw[t] & 0xffffu;
        unsigned e  = (lo >> 7) & 0xffu;
        int pl = ((lo & 0x7fffu) == 0u || (e >= 100u && e <= 140u)) ? 1 : 0;
        atomicAdd(&vote, pl);
    }
    __syncthreads();
    if (t == 0) flags[1] = (vote < 128) ? 1 : 0;
}

// ---------------------------------------------------------------- prep ∥ bucket scatter
// Blocks [0, nsb): bucket scatter of packed (src,dst) pairs, LDS-staged:
//   phase1 count+rank -> scan -> global base -> LDS bucket-sorted stage ->
//   per-bucket wave-cooperative coalesced copy-out.
// Blocks [nsb, nsb+NPREP): weight prep — all from RAW inputs, no internal deps.
//   w1x: rows 0-127 = W1^T; 128+h/136+h = va1s hi/lo; 144+h/152+h = va1d hi/lo
//   w2x: rows 0-31 = W2^T; 32/33 = va2s hi/lo; 34/35 = va2d hi/lo; 36-47 zero
// gcur[b] holds per-bucket COUNTS (zeroed by detect); pairs base = b*BCAP.
#define WTS_TOTAL 20993
__global__ __launch_bounds__(256) void prep_scatter_kernel(
        const void* __restrict__ ei, const int* __restrict__ flags,
        int* __restrict__ gcur, unsigned* __restrict__ pairs, int E, int Et, int nsb,
        const void* W1, const void* W2, const void* a1s, const void* a1d,
        const void* b1, const void* a2s, const void* a2d, const void* b2,
        const void* Wh, const void* bh,
        float* __restrict__ w, unsigned short* __restrict__ w1x,
        unsigned short* __restrict__ w2x){
    const int t = threadIdx.x;
    if ((int)blockIdx.x < nsb){
        // ---------------- scatter ----------------
        __shared__ int cnt[256];            // bucket counts (196 used)
        __shared__ int scn[256];            // inclusive scan
        __shared__ int base[NBK];           // global base within bucket
        __shared__ unsigned stage[4096];    // bucket-sorted pairs (16 KB)
        cnt[t] = 0;
        __syncthreads();
        const int is64 = flags[0];
        const int e0 = blockIdx.x * 4096;
        const int nE = min(4096, Et - e0);
        int2 sd[16];
        int  rk[16];
#pragma unroll
        for (int k = 0; k < 16; k++){
            int j = t + k * 256;
            if (j < nE){
                int e = e0 + j, s, d;
                if (e >= E){ s = e - E; d = s; }
                else if (is64){
                    const long long* p = (const long long*)ei;
                    s = (int)p[e]; d = (int)p[(size_t)E + e];
                } else {
                    const int* p = (const int*)ei;
                    s = p[e]; d = p[(size_t)E + e];
                }
                sd[k] = make_int2(s, d);
                rk[k] = atomicAdd(&cnt[d >> BWSH], 1);
            } else sd[k].y = -1;
        }
        __syncthreads();
        int v = cnt[t];
        scn[t] = v;
        __syncthreads();
        for (int off = 1; off < 256; off <<= 1){
            int x = (t >= off) ? scn[t - off] : 0;
            __syncthreads();
            scn[t] += x;
            __syncthreads();
        }
        if (t < NBK) base[t] = cnt[t] ? atomicAdd(&gcur[t], cnt[t]) : 0;
        __syncthreads();
        // LDS bucket-sorted stage
#pragma unroll
        for (int k = 0; k < 16; k++){
            if (sd[k].y >= 0){
                int b = sd[k].y >> BWSH;
                stage[(scn[b] - cnt[b]) + rk[k]] =
                    ((unsigned)sd[k].x << BWSH) | (unsigned)(sd[k].y & 511);
            }
        }
        __syncthreads();
        // per-bucket coalesced copy-out: wave wv handles buckets wv, wv+4, ...
        const int wv = t >> 6, lane = t & 63;
        for (int b = wv; b < NBK; b += 4){
            const int c  = cnt[b];
            const int sb = scn[b] - c;
            unsigned* gp = pairs + (size_t)b * BCAP + base[b];
            const unsigned* sp = stage + sb;
            for (int i = lane; i < c; i += 64) gp[i] = sp[i];
        }
    } else {
        // ---------------- prep (grid-stride over NPREP blocks) ----------------
        const int p   = blockIdx.x - nsb;
        const int tid = p * 256 + t;
        const int NT  = NPREP * 256;
        const int isf = flags[1];
        // wts tail: indices 20480..20992 (attn vecs + biases), relative i in [0,513)
        for (int i = tid; i < 513; i += NT){
            int gi = 20480 + i;
            const void* src; int off;
            if      (gi < 20608){ src = a1s; off = gi - 20480; }
            else if (gi < 20736){ src = a1d; off = gi - 20608; }
            else if (gi < 20864){ src = b1;  off = gi - 20736; }
            else if (gi < 20896){ src = a2s; off = gi - 20864; }
            else if (gi < 20928){ src = a2d; off = gi - 20896; }
            else if (gi < 20960){ src = b2;  off = gi - 20928; }
            else if (gi < 20992){ src = Wh;  off = gi - 20960; }
            else                { src = bh;  off = 0; }
            w[gi] = ldraw(src, off, isf);
        }
        // W1^T bf16
        for (int i = tid; i < 16384; i += NT){
            int c = i >> 7, k = i & 127;
            w1x[i] = f2bf(ldraw(W1, k*128 + c, isf));
        }
        // W2^T bf16 + zero pad rows 36..47
        for (int i = tid; i < 4096; i += NT){
            int c = i >> 7, k = i & 127;
            w2x[i] = f2bf(ldraw(W2, k*32 + c, isf));
        }
        for (int i = tid; i < 12*128; i += NT) w2x[36*128 + i] = 0;
        // fused logit vectors layer 1 (from raw inputs)
        for (int i = tid; i < 1024; i += NT){          // i = h*128 + k
            int h = i >> 7, k = i & 127;
            float ss = 0.f, dd = 0.f;
#pragma unroll
            for (int j = 0; j < 16; j++){
                float hv = ldraw(W1, k*128 + h*16 + j, isf);
                ss += hv * ldraw(a1s, h*16 + j, isf);
                dd += hv * ldraw(a1d, h*16 + j, isf);
            }
            unsigned short sh = f2bf(ss), dh = f2bf(dd);
            w1x[(128+h)*128 + k] = sh;
            w1x[(136+h)*128 + k] = f2bf(ss - bfs2f(sh));
            w1x[(144+h)*128 + k] = dh;
            w1x[(152+h)*128 + k] = f2bf(dd - bfs2f(dh));
        }
        // fused logit vectors layer 2
        for (int k = tid; k < 128; k += NT){
            float ss = 0.f, dd = 0.f;
#pragma unroll
            for (int j = 0; j < 32; j++){
                float hv = ldraw(W2, k*32 + j, isf);
                ss += hv * ldraw(a2s, j, isf);
                dd += hv * ldraw(a2d, j, isf);
            }
            unsigned short sh = f2bf(ss), dh = f2bf(dd);
            w2x[32*128 + k] = sh;
            w2x[33*128 + k] = f2bf(ss - bfs2f(sh));
            w2x[34*128 + k] = dh;
            w2x[35*128 + k] = f2bf(dd - bfs2f(dh));
        }
    }
}

// ---------------------------------------------------------------- csr_build ∥ GEMM1
// Blocks [0, NBK): per-bucket CSR build (gcur holds counts). Blocks [NBK, ...): MFMA
// GEMM1 + fused attn1 logits. Shared-mem union (52224 B = gemm1's requirement).
__global__ __launch_bounds__(256) void g1csr_kernel(
        const unsigned* __restrict__ pairs, const int* __restrict__ gcur,
        int* __restrict__ rowptr, int* __restrict__ csr_src, int Nn,
        const void* __restrict__ xv, const unsigned short* __restrict__ w1x,
        const int* __restrict__ flags, __hip_bfloat16* __restrict__ h1b,
        float* __restrict__ as1, float* __restrict__ ad1){
    __shared__ __align__(16) char smem[52224];
    const int t = threadIdx.x;
    if ((int)blockIdx.x < NBK){
        // ---------------- csr_build ----------------
        int* ssz   = (int*)smem;           // 256
        int* sscan = ssz + 256;            // 256
        int* cnt   = sscan + 256;          // 512
        int* sh    = cnt + 512;            // 256
        const int b = blockIdx.x;
        int v = (t < NBK) ? gcur[t] : 0;
        ssz[t] = v; sscan[t] = v;
        __syncthreads();
        for (int off = 1; off < 256; off <<= 1){
            int x = (t >= off) ? sscan[t - off] : 0;
            __syncthreads();
            sscan[t] += x;
            __syncthreads();
        }
        const int sz = ssz[b];
        const int eb = (b == 0) ? 0 : sscan[b - 1];
        if (b == 0 && t == 0) rowptr[Nn] = sscan[NBK - 1];
        const unsigned* pp = pairs + (size_t)b * BCAP;
        cnt[t] = 0; cnt[t + 256] = 0;
        __syncthreads();
        for (int i = t; i < sz; i += 256) atomicAdd(&cnt[pp[i] & 511u], 1);
        __syncthreads();
        int l0 = 2*t, l1 = 2*t + 1;
        int s0 = cnt[l0], s1 = cnt[l1], ts = s0 + s1;
        sh[t] = ts; __syncthreads();
        for (int off = 1; off < 256; off <<= 1){
            int x = (t >= off) ? sh[t - off] : 0;
            __syncthreads();
            sh[t] += x;
            __syncthreads();
        }
        int excl = sh[t] - ts;
        __syncthreads();
        cnt[l0] = eb + excl;
        cnt[l1] = eb + excl + s0;
        int n0 = (b << BWSH) + l0, n1 = (b << BWSH) + l1;
        if (n0 < Nn) rowptr[n0] = cnt[l0];
        if (n1 < Nn) rowptr[n1] = cnt[l1];
        __syncthreads();
        for (int i = t; i < sz; i += 256){
            unsigned sd = pp[i];
            int pos = atomicAdd(&cnt[sd & 511u], 1);
            csr_src[pos] = (int)(sd >> BWSH);
        }
    } else {
        // ---------------- gemm1 (MFMA) + attn1 ----------------
        __bf16* xls = (__bf16*)smem;                    // 64*XS = 17408 B
        __bf16* wls = (__bf16*)(smem + 64 * XS * 2);    // 128*XS = 34816 B
        const int row0 = ((int)blockIdx.x - NBK) * 64;
        const int n = Nn;

#pragma unroll
        for (int k = 0; k < 8; k++){
            int e = (t + k * 256) * 8;
            int c = e >> 7, kk = e & 127;
            *(uint4*)(&wls[c * XS + kk]) = *(const uint4*)(w1x + e);
        }
        if (row0 + 64 <= n){
            if (flags[1]){                              // fp32, float4 loads
                const float* xp = (const float*)xv + (size_t)row0 * 128;
#pragma unroll
                for (int k = 0; k < 8; k++){
                    int e = (t + k * 256) * 4;
                    int row = e >> 7, col = e & 127;
                    float4 vv = *(const float4*)(xp + e);
                    uint2 o;
                    o.x = (unsigned)f2bf(vv.x) | ((unsigned)f2bf(vv.y) << 16);
                    o.y = (unsigned)f2bf(vv.z) | ((unsigned)f2bf(vv.w) << 16);
                    *(uint2*)(&xls[row * XS + col]) = o;
                }
            } else {                                    // bf16, uint4 loads
                const unsigned short* xp = (const unsigned short*)xv + (size_t)row0 * 128;
#pragma unroll
                for (int k = 0; k < 4; k++){
                    int e = (t + k * 256) * 8;
                    int row = e >> 7, col = e & 127;
                    *(uint4*)(&xls[row * XS + col]) = *(const uint4*)(xp + e);
                }
            }
        } else {
            const int limit = (n - row0) * 128;
            if (flags[1]){
                const float* xp = (const float*)xv + (size_t)row0 * 128;
                for (int i = t; i < 64 * 128; i += 256){
                    float v = (i < limit) ? xp[i] : 0.f;
                    xls[(i >> 7) * XS + (i & 127)] = (__bf16)v;
                }
            } else {
                const unsigned short* xp = (const unsigned short*)xv + (size_t)row0 * 128;
                for (int i = t; i < 64 * 128; i += 256){
                    unsigned short v = (i < limit) ? xp[i] : (unsigned short)0;
                    ((unsigned short*)xls)[(i >> 7) * XS + (i & 127)] = v;
                }
            }
        }
        __syncthreads();

        const int w    = t >> 6;
        const int lane = t & 63;
        const int l15  = lane & 15;
        const int quad = lane >> 4;

        f32x4 acc[8] = {};
        f32x4 accS = {}, accD = {};
        const __bf16* xbase = &xls[(w * 16 + l15) * XS + quad * 8];
        const __bf16* wbase = &wls[l15 * XS + quad * 8];
        const unsigned short* vsrow = w1x + (128 + l15) * 128 + quad * 8;
        const unsigned short* vdrow = w1x + (144 + l15) * 128 + quad * 8;

#pragma unroll
        for (int ks = 0; ks < 4; ks++){
            bf16x8 af = *(const bf16x8*)(xbase + ks * 32);
#pragma unroll
            for (int tt = 0; tt < 8; tt++){
                bf16x8 bfr = *(const bf16x8*)(wbase + tt * 16 * XS + ks * 32);
                acc[tt] = __builtin_amdgcn_mfma_f32_16x16x32_bf16(af, bfr, acc[tt], 0, 0, 0);
            }
            bf16x8 bS = *(const bf16x8*)(vsrow + ks * 32);
            bf16x8 bD = *(const bf16x8*)(vdrow + ks * 32);
            accS = __builtin_amdgcn_mfma_f32_16x16x32_bf16(af, bS, accS, 0, 0, 0);
            accD = __builtin_amdgcn_mfma_f32_16x16x32_bf16(af, bD, accD, 0, 0, 0);
        }

#pragma unroll
        for (int tt = 0; tt < 8; tt++){
            int col = tt * 16 + l15;
#pragma unroll
            for (int r = 0; r < 4; r++){
                int row = row0 + w * 16 + quad * 4 + r;
                if (row < n) h1b[(size_t)row * 128 + col] = __float2bfloat16(acc[tt][r]);
            }
        }
#pragma unroll
        for (int r = 0; r < 4; r++){
            float vs = accS[r] + __shfl_xor(accS[r], 8);   // hi + lo
            float vd = accD[r] + __shfl_xor(accD[r], 8);
            int row = row0 + w * 16 + quad * 4 + r;
            if (l15 < 8 && row < n){
                as1[(size_t)row * 8 + l15] = vs;
                ad1[(size_t)row * 8 + l15] = vd;
            }
        }
    }
}

// ---------------------------------------------------------------- gather L1 + GEMM2 + attn2 (fused, MFMA epilogue)
// Per wave: one dst node, 8 edge slots (g=lane>>3), 8 lanes/edge, 16 ch/lane, csr prefetch.
// Epilogue: out1 rows (bias+ELU, bf16) -> swizzled LDS tile (16 rows: 4 real + 12 zero);
// waves 0-2 each run 4 MFMAs (one 16-col tile x K=128) computing h2 + attn2 logits.
// out1u never touches global memory; gemm2 kernel is deleted.
__global__ __launch_bounds__(256) void gather1_kernel(const int* __restrict__ rowptr,
                                                      const int* __restrict__ csr_src,
                                                      const float* __restrict__ as1,
                                                      const float* __restrict__ ad1,
                                                      const unsigned* __restrict__ h1u,
                                                      const float* __restrict__ b1,
                                                      const unsigned short* __restrict__ w2x,
                                                      __hip_bfloat16* __restrict__ h2b,
                                                      float* __restrict__ as2,
                                                      float* __restrict__ ad2, int n){
    __shared__ __align__(16) unsigned als[16 * 64];   // 16 rows x 128 bf16 (4 KB), XOR-swizzled
    const int t = threadIdx.x;
    // zero-init (rows 4-15 stay zero; rows 0-3 overwritten by their own wave below)
    als[t] = 0u; als[t + 256] = 0u; als[t + 512] = 0u; als[t + 768] = 0u;
    const int wv   = t >> 6;
    const int wid  = blockIdx.x * 4 + wv;
    const int lane = t & 63;
    const int g    = lane >> 3;    // edge slot 0..7
    const int h    = lane & 7;     // head (= channel group h*16..h*16+15)
    int start = 0, end = 0;
    float adv = 0.f;
    if (wid < n){
        start = rowptr[wid]; end = rowptr[wid + 1];
        adv = ad1[(size_t)wid * 8 + h];
    }
    float den = 0.f;
    float num[16] = {0.f,0.f,0.f,0.f,0.f,0.f,0.f,0.f,
                     0.f,0.f,0.f,0.f,0.f,0.f,0.f,0.f};
    int j   = start + g;
    int src = (j < end) ? __builtin_nontemporal_load(csr_src + j) : -1;
    const int iters = (end - start + 7) >> 3;
#pragma unroll 2
    for (int it = 0; it < iters; ++it){
        const int jn   = j + 8;
        const int srcn = (jn < end) ? __builtin_nontemporal_load(csr_src + jn) : -1;
        if (src >= 0){
            const unsigned* hp = h1u + (size_t)src * 64 + h * 8;
            uint4 hv0 = *(const uint4*)(hp);
            uint4 hv1 = *(const uint4*)(hp + 4);
            float u = lrelu(as1[src * 8 + h] + adv);
            float w = __expf(u);
            den += w;
            num[0]  += w * lo_bf(hv0.x); num[1]  += w * hi_bf(hv0.x);
            num[2]  += w * lo_bf(hv0.y); num[3]  += w * hi_bf(hv0.y);
            num[4]  += w * lo_bf(hv0.z); num[5]  += w * hi_bf(hv0.z);
            num[6]  += w * lo_bf(hv0.w); num[7]  += w * hi_bf(hv0.w);
            num[8]  += w * lo_bf(hv1.x); num[9]  += w * hi_bf(hv1.x);
            num[10] += w * lo_bf(hv1.y); num[11] += w * hi_bf(hv1.y);
            num[12] += w * lo_bf(hv1.z); num[13] += w * hi_bf(hv1.z);
            num[14] += w * lo_bf(hv1.w); num[15] += w * hi_bf(hv1.w);
        }
        j = jn; src = srcn;
    }
    // reduce over edge slots (lane bits 3,4,5) — preserves head h
    den += __shfl_xor(den, 8); den += __shfl_xor(den, 16); den += __shfl_xor(den, 32);
#pragma unroll
    for (int k = 0; k < 16; k++){
        num[k] += __shfl_xor(num[k], 8);
        num[k] += __shfl_xor(num[k], 16);
        num[k] += __shfl_xor(num[k], 32);
    }
    if (g == 0 && wid < n){               // lanes 0..7: bias+ELU 16 ch -> swizzled LDS row wv
        const int ch0 = h * 16;
        float inv = 1.f / (den + 1e-16f);
        unsigned op[8];
#pragma unroll
        for (int m = 0; m < 8; m++){
            float r0 = num[2*m]   * inv + b1[ch0 + 2*m];
            float r1 = num[2*m+1] * inv + b1[ch0 + 2*m + 1];
            r0 = r0 > 0.f ? r0 : __expf(r0) - 1.f;
            r1 = r1 > 0.f ? r1 : __expf(r1) - 1.f;
            op[m] = (unsigned)f2bf(r0) | ((unsigned)f2bf(r1) << 16);
        }
        const int sw = (wv & 3) << 2;     // row-XOR swizzle on 16B chunks
        unsigned* ap = als + wv * 64;
        *(uint4*)(ap + ((h * 8)     ^ sw)) = make_uint4(op[0], op[1], op[2], op[3]);
        *(uint4*)(ap + ((h * 8 + 4) ^ sw)) = make_uint4(op[4], op[5], op[6], op[7]);
    }
    __syncthreads();
    // -------- fused GEMM2 (MFMA): wave wv<3 computes col-tile wv (cols wv*16..+15) --------
    // A: als rows = nodes (0-3 real, 4-15 zero); B: w2x rows (output cols), K=128.
    if (wv < 3){
        const int l15  = lane & 15;
        const int quad = lane >> 4;
        const int swr  = (l15 & 3) << 2;
        f32x4 acc = {};
        const unsigned short* brow = w2x + (wv * 16 + l15) * 128 + quad * 8;
#pragma unroll
        for (int ks = 0; ks < 4; ks++){
            const unsigned* ap = als + l15 * 64 + (((quad * 4) + ks * 16) ^ swr);
            bf16x8 af = *(const bf16x8*)ap;
            bf16x8 bfr = *(const bf16x8*)(brow + ks * 32);
            acc = __builtin_amdgcn_mfma_f32_16x16x32_bf16(af, bfr, acc, 0, 0, 0);
        }
        if (wv < 2){                      // h2 channels: col = wv*16 + l15, rows 0-3 (quad 0)
            if (quad == 0){
#pragma unroll
                for (int r = 0; r < 4; r++){
                    int node = blockIdx.x * 4 + r;
                    if (node < n)
                        h2b[(size_t)node * 32 + wv * 16 + l15] = __float2bfloat16(acc[r]);
                }
            }
        } else {                          // logit tile (w2x rows 32-47): hi+lo pairs
#pragma unroll
            for (int r = 0; r < 4; r++){
                float vE = acc[r] + __shfl_xor(acc[r], 1);
                int node = blockIdx.x * 4 + r;
                if (quad == 0 && node < n){
                    if (l15 == 0) as2[node] = vE;     // cols 32+33
                    if (l15 == 2) ad2[node] = vE;     // cols 34+35
                }
            }
        }
    }
}

// ---------------------------------------------------------------- gather L2 + head (fused)
// One wave per dst node: 16 edge slots (g=lane>>2), 4 lanes/edge, 8 ch/lane (uint4),
// next-edge csr_src prefetch (nontemporal).
__global__ __launch_bounds__(256) void gather2_kernel(const int* __restrict__ rowptr,
                                                      const int* __restrict__ csr_src,
                                                      const float* __restrict__ as2,
                                                      const float* __restrict__ ad2,
                                                      const unsigned* __restrict__ h2u,
                                                      const float* __restrict__ b2,
                                                      const float* __restrict__ Wh,
                                                      const float* __restrict__ bh,
                                                      const int* __restrict__ flags,
                                                      void* __restrict__ out, int n){
    int wid = blockIdx.x * 4 + (threadIdx.x >> 6);
    if (wid >= n) return;
    const int lane = threadIdx.x & 63;
    const int g = lane >> 2;       // edge slot 0..15
    const int c = lane & 3;        // channel quad (channels c*8..c*8+7)
    const int start = rowptr[wid], end = rowptr[wid + 1];
    const float adv = ad2[wid];
    float den = 0.f;
    float num[8] = {0.f,0.f,0.f,0.f,0.f,0.f,0.f,0.f};
    int j   = start + g;
    int src = (j < end) ? __builtin_nontemporal_load(csr_src + j) : -1;
    const int iters = (end - start + 15) >> 4;
#pragma unroll 2
    for (int it = 0; it < iters; ++it){
        const int jn   = j + 16;
        const int srcn = (jn < end) ? __builtin_nontemporal_load(csr_src + jn) : -1;
        if (src >= 0){
            uint4 hv = *(const uint4*)(h2u + (size_t)src * 16 + c * 4);
            float u = lrelu(as2[src] + adv);
            float w = __expf(u);
            den += w;
            num[0] += w * lo_bf(hv.x); num[1] += w * hi_bf(hv.x);
            num[2] += w * lo_bf(hv.y); num[3] += w * hi_bf(hv.y);
            num[4] += w * lo_bf(hv.z); num[5] += w * hi_bf(hv.z);
            num[6] += w * lo_bf(hv.w); num[7] += w * hi_bf(hv.w);
        }
        j = jn; src = srcn;
    }
    // reduce over edge slots (lane bits 2..5) — preserves channel quad c
    den += __shfl_xor(den, 4); den += __shfl_xor(den, 8);
    den += __shfl_xor(den, 16); den += __shfl_xor(den, 32);
#pragma unroll
    for (int k = 0; k < 8; k++){
        num[k] += __shfl_xor(num[k], 4);
        num[k] += __shfl_xor(num[k], 8);
        num[k] += __shfl_xor(num[k], 16);
        num[k] += __shfl_xor(num[k], 32);
    }
    float p = 0.f;
    if (g == 0){                   // lanes 0..3 hold the full sums
        const int ch0 = c * 8;
        float inv = 1.f / (den + 1e-16f);
#pragma unroll
        for (int k = 0; k < 8; k++){
            float v = num[k] * inv + b2[ch0 + k];
            v = v > 0.f ? v : __expf(v) - 1.f;
            p += v * Wh[ch0 + k];
        }
    }
    p += __shfl_xor(p, 1); p += __shfl_xor(p, 2);
    if (lane == 0){
        float r = p + bh[0];
        if (flags[1]) ((float*)out)[wid] = r;
        else          ((__hip_bfloat16*)out)[wid] = __float2bfloat16(r);
    }
}

extern "C" void kernel_launch(void* const* d_in, const int* in_sizes, int n_in,
                              void* d_out, int out_size, void* d_ws, size_t ws_size,
                              hipStream_t stream){
    const void* x   = d_in[0];
    const void* ei  = d_in[1];

    const int Nn = in_sizes[0] / 128;     // 100000
    const int Ee = in_sizes[1] / 2;       // 1600000
    const int Et = Ee + Nn;               // 1700000
    const int nsb = (Et + 4095) / 4096;   // scatter blocks

    char* ws = (char*)d_ws;
    auto al = [](size_t v){ return (v + 255) & ~(size_t)255; };
    size_t off = 0;
    int*      flags  = (int*)(ws + off);      off = al(off + 16);
    float*    wts    = (float*)(ws + off);    off = al(off + (size_t)WTS_TOTAL * 4);
    unsigned short* w1x = (unsigned short*)(ws + off); off = al(off + 160 * 128 * 2);
    unsigned short* w2x = (unsigned short*)(ws + off); off = al(off + 48 * 128 * 2);
    int*      gcur   = (int*)(ws + off);      off = al(off + (size_t)NBK * 4);
    int*      rowptr = (int*)(ws + off);      off = al(off + (size_t)(Nn + 1) * 4);
    int*      csrs   = (int*)(ws + off);      off = al(off + (size_t)Et * 4);
    unsigned* pairs  = (unsigned*)(ws + off); off = al(off + (size_t)NBK * BCAP * 4);
    __hip_bfloat16* h1b = (__hip_bfloat16*)(ws + off); off = al(off + (size_t)Nn * 128 * 2);
    float* as1  = (float*)(ws + off); off = al(off + (size_t)Nn * 8 * 4);
    float* ad1  = (float*)(ws + off); off = al(off + (size_t)Nn * 8 * 4);
    // layer-2 tables (written by fused gather1 while h1b is live -> own region)
    __hip_bfloat16* h2b = (__hip_bfloat16*)(ws + off); off = al(off + (size_t)Nn * 32 * 2);
    float* as2  = (float*)(ws + off); off = al(off + (size_t)Nn * 4);
    float* ad2  = (float*)(ws + off); off = al(off + (size_t)Nn * 4);

    float* b1f  = wts + 20736;
    float* b2f  = wts + 20928;
    float* Whf  = wts + 20960;
    float* bhf  = wts + 20992;

    // 1) detect dtypes + zero bucket counters
    detect_kernel<<<1, 256, 0, stream>>>((const unsigned*)ei, (const unsigned*)x, flags, gcur);

    // 2) weight prep ∥ LDS-staged bucket scatter (block-specialized)
    prep_scatter_kernel<<<nsb + NPREP, 256, 0, stream>>>(ei, flags, gcur, pairs, Ee, Et, nsb,
        d_in[2], d_in[6], d_in[3], d_in[4], d_in[5], d_in[7], d_in[8], d_in[9],
        d_in[10], d_in[11], wts, w1x, w2x);

    // 3) per-bucket CSR build ∥ GEMM1+attn1 (block-specialized)
    g1csr_kernel<<<NBK + (Nn + 63) / 64, 256, 0, stream>>>(pairs, gcur, rowptr, csrs, Nn,
        x, w1x, flags, h1b, as1, ad1);

    // 4) gather layer 1 + fused GEMM2/attn2 (MFMA epilogue) — gemm2 kernel deleted
    gather1_kernel<<<(Nn + 3) / 4, 256, 0, stream>>>(rowptr, csrs, as1, ad1,
                                                     (const unsigned*)h1b, b1f,
                                                     w2x, h2b, as2, ad2, Nn);

    // 5) gather layer 2 + ordinal head
    gather2_kernel<<<(Nn + 3) / 4, 256, 0, stream>>>(rowptr, csrs, as2, ad2,
                                                     (const unsigned*)h2b, b2f,
                                                     Whf, bhf, flags, d_out, Nn);
}

// Round 10
// 279.993 us; speedup vs baseline: 1.0999x; 1.0999x over previous
//
#include <hip/hip_runtime.h>
#include <hip/hip_bf16.h>
#include <stdint.h>
#include <stddef.h>

#define NEG_SLOPE 0.2f
#define XS 136   // padded LDS row stride in bf16 elems (272 B, 16B-aligned, kills 256B bank alias)

// CSR bucket build: bucket = dst >> 9 (512 nodes/bucket), 196 buckets for N=100k.
#define NBK   196
#define BWSH  9
#define BCAP  12288
#define NPREP 64   // prep blocks appended after scatter blocks

typedef __bf16 bf16x8 __attribute__((ext_vector_type(8)));
typedef float  f32x4  __attribute__((ext_vector_type(4)));

__device__ __forceinline__ float bf2f(__hip_bfloat16 b){ return __bfloat162float(b); }
__device__ __forceinline__ float lo_bf(unsigned u){ return __uint_as_float(u << 16); }
__device__ __forceinline__ float hi_bf(unsigned u){ return __uint_as_float(u & 0xffff0000u); }
__device__ __forceinline__ float lrelu(float u){ return fmaxf(u, NEG_SLOPE * u); }
__device__ __forceinline__ unsigned short f2bf(float f){           // RNE bf16
    unsigned u = __float_as_uint(f);
    return (unsigned short)((u + 0x7fffu + ((u >> 16) & 1u)) >> 16);
}
__device__ __forceinline__ float bfs2f(unsigned short s){ return __uint_as_float((unsigned)s << 16); }
__device__ __forceinline__ float ldraw(const void* p, int i, int isf){
    return isf ? ((const float*)p)[i] : bf2f(((const __hip_bfloat16*)p)[i]);
}

// ---------------------------------------------------------------- detect (1 block)
// flags[0]: 1 if edge_index is int64; flags[1]: 1 if floats are fp32. + gcur init.
__global__ void detect_kernel(const unsigned* __restrict__ ei,
                              const unsigned* __restrict__ xw,
                              int* __restrict__ flags,
                              int* __restrict__ gcur){
    __shared__ int vote;
    const int t = threadIdx.x;
    if (t == 0) vote = 0;
    if (t < NBK) gcur[t] = t * BCAP;
    __syncthreads();
    if (t < 64){
        unsigned long long m = __ballot(ei[2*t + 1] != 0u);
        if (t == 0) flags[0] = (m == 0ull) ? 1 : 0;
    }
    {
        unsigned lo = xw[t] & 0xffffu;
        unsigned e  = (lo >> 7) & 0xffu;
        int pl = ((lo & 0x7fffu) == 0u || (e >= 100u && e <= 140u)) ? 1 : 0;
        atomicAdd(&vote, pl);
    }
    __syncthreads();
    if (t == 0) flags[1] = (vote < 128) ? 1 : 0;
}

// ---------------------------------------------------------------- prep ∥ bucket scatter
// Blocks [0, nsb): register-resident bucket scatter of packed (src,dst) pairs.
// Blocks [nsb, nsb+NPREP): weight prep — all from RAW inputs, no internal deps:
//   wts tail (biases/attn vecs), W1^T/W2^T bf16, fused logit vectors (hi/lo).
//   w1x: rows 0-127 = W1^T; 128+h/136+h = va1s hi/lo; 144+h/152+h = va1d hi/lo
//   w2x: rows 0-31 = W2^T; 32/33 = va2s hi/lo; 34/35 = va2d hi/lo; 36-47 zero
#define WTS_TOTAL 20993
__global__ __launch_bounds__(256) void prep_scatter_kernel(
        const void* __restrict__ ei, const int* __restrict__ flags,
        int* __restrict__ gcur, unsigned* __restrict__ pairs, int E, int Et, int nsb,
        const void* W1, const void* W2, const void* a1s, const void* a1d,
        const void* b1, const void* a2s, const void* a2d, const void* b2,
        const void* Wh, const void* bh,
        float* __restrict__ w, unsigned short* __restrict__ w1x,
        unsigned short* __restrict__ w2x){
    const int t = threadIdx.x;
    if ((int)blockIdx.x < nsb){
        // ---------------- scatter ----------------
        __shared__ int cnt[NBK], base[NBK], lcnt[NBK];
        const int e0 = blockIdx.x * 4096;
        const int nE = min(4096, Et - e0);
        for (int i = t; i < NBK; i += 256){ cnt[i] = 0; lcnt[i] = 0; }
        __syncthreads();
        const int is64 = flags[0];
        int2 sd[16];
#pragma unroll
        for (int k = 0; k < 16; k++){
            int j = t + k * 256;
            if (j < nE){
                int e = e0 + j, s, d;
                if (e >= E){ s = e - E; d = s; }
                else if (is64){
                    const long long* p = (const long long*)ei;
                    s = (int)p[e]; d = (int)p[(size_t)E + e];
                } else {
                    const int* p = (const int*)ei;
                    s = p[e]; d = p[(size_t)E + e];
                }
                sd[k] = make_int2(s, d);
                atomicAdd(&cnt[d >> BWSH], 1);
            } else sd[k].y = -1;
        }
        __syncthreads();
        for (int b = t; b < NBK; b += 256)
            base[b] = cnt[b] ? atomicAdd(&gcur[b], cnt[b]) : 0;
        __syncthreads();
#pragma unroll
        for (int k = 0; k < 16; k++){
            if (sd[k].y >= 0){
                int b = sd[k].y >> BWSH;
                int r = atomicAdd(&lcnt[b], 1);
                pairs[(size_t)base[b] + r] = ((unsigned)sd[k].x << BWSH) | (unsigned)(sd[k].y & 511);
            }
        }
    } else {
        // ---------------- prep (grid-stride over NPREP blocks) ----------------
        const int p   = blockIdx.x - nsb;
        const int tid = p * 256 + t;
        const int NT  = NPREP * 256;
        const int isf = flags[1];
        // wts tail: indices 20480..20992 (attn vecs + biases), relative i in [0,513)
        for (int i = tid; i < 513; i += NT){
            int gi = 20480 + i;
            const void* src; int off;
            if      (gi < 20608){ src = a1s; off = gi - 20480; }
            else if (gi < 20736){ src = a1d; off = gi - 20608; }
            else if (gi < 20864){ src = b1;  off = gi - 20736; }
            else if (gi < 20896){ src = a2s; off = gi - 20864; }
            else if (gi < 20928){ src = a2d; off = gi - 20896; }
            else if (gi < 20960){ src = b2;  off = gi - 20928; }
            else if (gi < 20992){ src = Wh;  off = gi - 20960; }
            else                { src = bh;  off = 0; }
            w[gi] = ldraw(src, off, isf);
        }
        // W1^T bf16
        for (int i = tid; i < 16384; i += NT){
            int c = i >> 7, k = i & 127;
            w1x[i] = f2bf(ldraw(W1, k*128 + c, isf));
        }
        // W2^T bf16 + zero pad rows 36..47
        for (int i = tid; i < 4096; i += NT){
            int c = i >> 7, k = i & 127;
            w2x[i] = f2bf(ldraw(W2, k*32 + c, isf));
        }
        for (int i = tid; i < 12*128; i += NT) w2x[36*128 + i] = 0;
        // fused logit vectors layer 1 (from raw inputs)
        for (int i = tid; i < 1024; i += NT){          // i = h*128 + k
            int h = i >> 7, k = i & 127;
            float ss = 0.f, dd = 0.f;
#pragma unroll
            for (int j = 0; j < 16; j++){
                float hv = ldraw(W1, k*128 + h*16 + j, isf);
                ss += hv * ldraw(a1s, h*16 + j, isf);
                dd += hv * ldraw(a1d, h*16 + j, isf);
            }
            unsigned short sh = f2bf(ss), dh = f2bf(dd);
            w1x[(128+h)*128 + k] = sh;
            w1x[(136+h)*128 + k] = f2bf(ss - bfs2f(sh));
            w1x[(144+h)*128 + k] = dh;
            w1x[(152+h)*128 + k] = f2bf(dd - bfs2f(dh));
        }
        // fused logit vectors layer 2
        for (int k = tid; k < 128; k += NT){
            float ss = 0.f, dd = 0.f;
#pragma unroll
            for (int j = 0; j < 32; j++){
                float hv = ldraw(W2, k*32 + j, isf);
                ss += hv * ldraw(a2s, j, isf);
                dd += hv * ldraw(a2d, j, isf);
            }
            unsigned short sh = f2bf(ss), dh = f2bf(dd);
            w2x[32*128 + k] = sh;
            w2x[33*128 + k] = f2bf(ss - bfs2f(sh));
            w2x[34*128 + k] = dh;
            w2x[35*128 + k] = f2bf(dd - bfs2f(dh));
        }
    }
}

// ---------------------------------------------------------------- csr_build ∥ GEMM1
// Blocks [0, NBK): per-bucket CSR build. Blocks [NBK, NBK+gridGemm): MFMA GEMM1
// + fused attn1 logits. Shared-mem union (52224 B = gemm1's requirement).
__global__ __launch_bounds__(256) void g1csr_kernel(
        const unsigned* __restrict__ pairs, const int* __restrict__ gcur,
        int* __restrict__ rowptr, int* __restrict__ csr_src, int Nn,
        const void* __restrict__ xv, const unsigned short* __restrict__ w1x,
        const int* __restrict__ flags, __hip_bfloat16* __restrict__ h1b,
        float* __restrict__ as1, float* __restrict__ ad1){
    __shared__ __align__(16) char smem[52224];
    const int t = threadIdx.x;
    if ((int)blockIdx.x < NBK){
        // ---------------- csr_build ----------------
        int* ssz   = (int*)smem;           // 256
        int* sscan = ssz + 256;            // 256
        int* cnt   = sscan + 256;          // 512
        int* sh    = cnt + 512;            // 256
        const int b = blockIdx.x;
        int v = (t < NBK) ? (gcur[t] - t * BCAP) : 0;
        ssz[t] = v; sscan[t] = v;
        __syncthreads();
        for (int off = 1; off < 256; off <<= 1){
            int x = (t >= off) ? sscan[t - off] : 0;
            __syncthreads();
            sscan[t] += x;
            __syncthreads();
        }
        const int sz = ssz[b];
        const int eb = (b == 0) ? 0 : sscan[b - 1];
        if (b == 0 && t == 0) rowptr[Nn] = sscan[NBK - 1];
        const unsigned* pp = pairs + (size_t)b * BCAP;
        cnt[t] = 0; cnt[t + 256] = 0;
        __syncthreads();
        for (int i = t; i < sz; i += 256) atomicAdd(&cnt[pp[i] & 511u], 1);
        __syncthreads();
        int l0 = 2*t, l1 = 2*t + 1;
        int s0 = cnt[l0], s1 = cnt[l1], ts = s0 + s1;
        sh[t] = ts; __syncthreads();
        for (int off = 1; off < 256; off <<= 1){
            int x = (t >= off) ? sh[t - off] : 0;
            __syncthreads();
            sh[t] += x;
            __syncthreads();
        }
        int excl = sh[t] - ts;
        __syncthreads();
        cnt[l0] = eb + excl;
        cnt[l1] = eb + excl + s0;
        int n0 = (b << BWSH) + l0, n1 = (b << BWSH) + l1;
        if (n0 < Nn) rowptr[n0] = cnt[l0];
        if (n1 < Nn) rowptr[n1] = cnt[l1];
        __syncthreads();
        for (int i = t; i < sz; i += 256){
            unsigned sd = pp[i];
            int pos = atomicAdd(&cnt[sd & 511u], 1);
            csr_src[pos] = (int)(sd >> BWSH);
        }
    } else {
        // ---------------- gemm1 (MFMA) + attn1 ----------------
        __bf16* xls = (__bf16*)smem;                    // 64*XS = 17408 B
        __bf16* wls = (__bf16*)(smem + 64 * XS * 2);    // 128*XS = 34816 B
        const int row0 = ((int)blockIdx.x - NBK) * 64;
        const int n = Nn;

#pragma unroll
        for (int k = 0; k < 8; k++){
            int e = (t + k * 256) * 8;
            int c = e >> 7, kk = e & 127;
            *(uint4*)(&wls[c * XS + kk]) = *(const uint4*)(w1x + e);
        }
        if (row0 + 64 <= n){
            if (flags[1]){                              // fp32, float4 loads
                const float* xp = (const float*)xv + (size_t)row0 * 128;
#pragma unroll
                for (int k = 0; k < 8; k++){
                    int e = (t + k * 256) * 4;
                    int row = e >> 7, col = e & 127;
                    float4 vv = *(const float4*)(xp + e);
                    uint2 o;
                    o.x = (unsigned)f2bf(vv.x) | ((unsigned)f2bf(vv.y) << 16);
                    o.y = (unsigned)f2bf(vv.z) | ((unsigned)f2bf(vv.w) << 16);
                    *(uint2*)(&xls[row * XS + col]) = o;
                }
            } else {                                    // bf16, uint4 loads
                const unsigned short* xp = (const unsigned short*)xv + (size_t)row0 * 128;
#pragma unroll
                for (int k = 0; k < 4; k++){
                    int e = (t + k * 256) * 8;
                    int row = e >> 7, col = e & 127;
                    *(uint4*)(&xls[row * XS + col]) = *(const uint4*)(xp + e);
                }
            }
        } else {
            const int limit = (n - row0) * 128;
            if (flags[1]){
                const float* xp = (const float*)xv + (size_t)row0 * 128;
                for (int i = t; i < 64 * 128; i += 256){
                    float v = (i < limit) ? xp[i] : 0.f;
                    xls[(i >> 7) * XS + (i & 127)] = (__bf16)v;
                }
            } else {
                const unsigned short* xp = (const unsigned short*)xv + (size_t)row0 * 128;
                for (int i = t; i < 64 * 128; i += 256){
                    unsigned short v = (i < limit) ? xp[i] : (unsigned short)0;
                    ((unsigned short*)xls)[(i >> 7) * XS + (i & 127)] = v;
                }
            }
        }
        __syncthreads();

        const int w    = t >> 6;
        const int lane = t & 63;
        const int l15  = lane & 15;
        const int quad = lane >> 4;

        f32x4 acc[8] = {};
        f32x4 accS = {}, accD = {};
        const __bf16* xbase = &xls[(w * 16 + l15) * XS + quad * 8];
        const __bf16* wbase = &wls[l15 * XS + quad * 8];
        const unsigned short* vsrow = w1x + (128 + l15) * 128 + quad * 8;
        const unsigned short* vdrow = w1x + (144 + l15) * 128 + quad * 8;

#pragma unroll
        for (int ks = 0; ks < 4; ks++){
            bf16x8 af = *(const bf16x8*)(xbase + ks * 32);
#pragma unroll
            for (int tt = 0; tt < 8; tt++){
                bf16x8 bfr = *(const bf16x8*)(wbase + tt * 16 * XS + ks * 32);
                acc[tt] = __builtin_amdgcn_mfma_f32_16x16x32_bf16(af, bfr, acc[tt], 0, 0, 0);
            }
            bf16x8 bS = *(const bf16x8*)(vsrow + ks * 32);
            bf16x8 bD = *(const bf16x8*)(vdrow + ks * 32);
            accS = __builtin_amdgcn_mfma_f32_16x16x32_bf16(af, bS, accS, 0, 0, 0);
            accD = __builtin_amdgcn_mfma_f32_16x16x32_bf16(af, bD, accD, 0, 0, 0);
        }

#pragma unroll
        for (int tt = 0; tt < 8; tt++){
            int col = tt * 16 + l15;
#pragma unroll
            for (int r = 0; r < 4; r++){
                int row = row0 + w * 16 + quad * 4 + r;
                if (row < n) h1b[(size_t)row * 128 + col] = __float2bfloat16(acc[tt][r]);
            }
        }
#pragma unroll
        for (int r = 0; r < 4; r++){
            float vs = accS[r] + __shfl_xor(accS[r], 8);   // hi + lo
            float vd = accD[r] + __shfl_xor(accD[r], 8);
            int row = row0 + w * 16 + quad * 4 + r;
            if (l15 < 8 && row < n){
                as1[(size_t)row * 8 + l15] = vs;
                ad1[(size_t)row * 8 + l15] = vd;
            }
        }
    }
}

// ---------------------------------------------------------------- gather L1 (+bias+ELU)
// One wave per dst node: 8 edge slots (g=lane>>3), 8 lanes/edge, 16 ch/lane (2x uint4),
// next-edge csr_src prefetch. (R1 champion form — fabric-bound at 3.5 TB/s, unchanged.)
__global__ __launch_bounds__(256) void gather1_kernel(const int* __restrict__ rowptr,
                                                      const int* __restrict__ csr_src,
                                                      const float* __restrict__ as1,
                                                      const float* __restrict__ ad1,
                                                      const unsigned* __restrict__ h1u,
                                                      const float* __restrict__ b1,
                                                      unsigned* __restrict__ out1u, int n){
    int wid = blockIdx.x * 4 + (threadIdx.x >> 6);
    if (wid >= n) return;
    const int lane = threadIdx.x & 63;
    const int g    = lane >> 3;    // edge slot 0..7
    const int h    = lane & 7;     // head (= channel group h*16..h*16+15)
    const int start = rowptr[wid], end = rowptr[wid + 1];
    const float adv = ad1[(size_t)wid * 8 + h];
    float den = 0.f;
    float num[16] = {0.f,0.f,0.f,0.f,0.f,0.f,0.f,0.f,
                     0.f,0.f,0.f,0.f,0.f,0.f,0.f,0.f};
    int j   = start + g;
    int src = (j < end) ? csr_src[j] : -1;
    const int iters = (end - start + 7) >> 3;
#pragma unroll 2
    for (int it = 0; it < iters; ++it){
        const int jn   = j + 8;
        const int srcn = (jn < end) ? csr_src[jn] : -1;   // prefetch next edge index
        if (src >= 0){
            const unsigned* hp = h1u + (size_t)src * 64 + h * 8;
            uint4 hv0 = *(const uint4*)(hp);
            uint4 hv1 = *(const uint4*)(hp + 4);
            float u = lrelu(as1[src * 8 + h] + adv);
            float w = __expf(u);
            den += w;
            num[0]  += w * lo_bf(hv0.x); num[1]  += w * hi_bf(hv0.x);
            num[2]  += w * lo_bf(hv0.y); num[3]  += w * hi_bf(hv0.y);
            num[4]  += w * lo_bf(hv0.z); num[5]  += w * hi_bf(hv0.z);
            num[6]  += w * lo_bf(hv0.w); num[7]  += w * hi_bf(hv0.w);
            num[8]  += w * lo_bf(hv1.x); num[9]  += w * hi_bf(hv1.x);
            num[10] += w * lo_bf(hv1.y); num[11] += w * hi_bf(hv1.y);
            num[12] += w * lo_bf(hv1.z); num[13] += w * hi_bf(hv1.z);
            num[14] += w * lo_bf(hv1.w); num[15] += w * hi_bf(hv1.w);
        }
        j = jn; src = srcn;
    }
    // reduce over edge slots (lane bits 3,4,5) — preserves head h
    den += __shfl_xor(den, 8); den += __shfl_xor(den, 16); den += __shfl_xor(den, 32);
#pragma unroll
    for (int k = 0; k < 16; k++){
        num[k] += __shfl_xor(num[k], 8);
        num[k] += __shfl_xor(num[k], 16);
        num[k] += __shfl_xor(num[k], 32);
    }
    if (g == 0){                      // lanes 0..7: each writes 16 channels (32 B)
        const int ch0 = h * 16;
        float inv = 1.f / (den + 1e-16f);
        uint4 o0, o1;
        unsigned* op0 = (unsigned*)&o0;
        unsigned* op1 = (unsigned*)&o1;
#pragma unroll
        for (int m = 0; m < 4; m++){
            float r0 = num[2*m]   * inv + b1[ch0 + 2*m];
            float r1 = num[2*m+1] * inv + b1[ch0 + 2*m + 1];
            r0 = r0 > 0.f ? r0 : __expf(r0) - 1.f;
            r1 = r1 > 0.f ? r1 : __expf(r1) - 1.f;
            op0[m] = (unsigned)f2bf(r0) | ((unsigned)f2bf(r1) << 16);
        }
#pragma unroll
        for (int m = 4; m < 8; m++){
            float r0 = num[2*m]   * inv + b1[ch0 + 2*m];
            float r1 = num[2*m+1] * inv + b1[ch0 + 2*m + 1];
            r0 = r0 > 0.f ? r0 : __expf(r0) - 1.f;
            r1 = r1 > 0.f ? r1 : __expf(r1) - 1.f;
            op1[m - 4] = (unsigned)f2bf(r0) | ((unsigned)f2bf(r1) << 16);
        }
        unsigned* ob = out1u + (size_t)wid * 64 + h * 8;
        *(uint4*)(ob)     = o0;
        *(uint4*)(ob + 4) = o1;
    }
}

// ---------------------------------------------------------------- GEMM2 (MFMA) + attn2 fused
__global__ __launch_bounds__(256) void gemm2_kernel(const unsigned* __restrict__ out1u,
                                                    const unsigned short* __restrict__ w2x,
                                                    __hip_bfloat16* __restrict__ h2b,
                                                    float* __restrict__ as2,
                                                    float* __restrict__ ad2, int n){
    __shared__ __align__(16) __bf16 als[64 * XS];   // 17408 B
    __shared__ __align__(16) __bf16 wls[32 * XS];   // 8704 B
    const int t = threadIdx.x;
    const int row0 = blockIdx.x * 64;

#pragma unroll
    for (int k = 0; k < 2; k++){
        int e = (t + k * 256) * 8;
        int c = e >> 7, kk = e & 127;
        *(uint4*)(&wls[c * XS + kk]) = *(const uint4*)(w2x + e);
    }
    if (row0 + 64 <= n){
#pragma unroll
        for (int k = 0; k < 4; k++){
            int e = (t + k * 256) * 4;              // uint index
            int row = e >> 6, cu = e & 63;
            *(uint4*)(&((unsigned*)als)[row * 68 + cu]) =
                *(const uint4*)(out1u + (size_t)row0 * 64 + e);
        }
    } else {
        const int limit = (n - row0) * 64;
        for (int i = t; i < 64 * 64; i += 256){
            unsigned v = (i < limit) ? out1u[(size_t)row0 * 64 + i] : 0u;
            ((unsigned*)als)[(i >> 6) * 68 + (i & 63)] = v;
        }
    }
    __syncthreads();

    const int w    = t >> 6;
    const int lane = t & 63;
    const int l15  = lane & 15;
    const int quad = lane >> 4;

    f32x4 acc[2] = {};
    f32x4 accE = {};
    const __bf16* abase = &als[(w * 16 + l15) * XS + quad * 8];
    const __bf16* bbase = &wls[l15 * XS + quad * 8];
    const unsigned short* verow = w2x + (32 + l15) * 128 + quad * 8;

#pragma unroll
    for (int ks = 0; ks < 4; ks++){
        bf16x8 af = *(const bf16x8*)(abase + ks * 32);
#pragma unroll
        for (int tt = 0; tt < 2; tt++){
            bf16x8 bfr = *(const bf16x8*)(bbase + tt * 16 * XS + ks * 32);
            acc[tt] = __builtin_amdgcn_mfma_f32_16x16x32_bf16(af, bfr, acc[tt], 0, 0, 0);
        }
        bf16x8 bE = *(const bf16x8*)(verow + ks * 32);
        accE = __builtin_amdgcn_mfma_f32_16x16x32_bf16(af, bE, accE, 0, 0, 0);
    }

#pragma unroll
    for (int r = 0; r < 4; r++){
        int row = row0 + w * 16 + quad * 4 + r;
        if (row < n){
#pragma unroll
            for (int tt = 0; tt < 2; tt++){
                int col = tt * 16 + l15;
                h2b[(size_t)row * 32 + col] = __float2bfloat16(acc[tt][r]);
            }
        }
        float vE = accE[r] + __shfl_xor(accE[r], 1);  // hi + lo
        if (row < n){
            if (l15 == 0) as2[row] = vE;              // cols 32+33
            if (l15 == 2) ad2[row] = vE;              // cols 34+35
        }
    }
}

// ---------------------------------------------------------------- gather L2 + head (fused)
// TWO nodes per wave (halved wave overhead): lanes 0-31 -> node wid0, 32-63 -> wid0+1.
// Within each 32-lane half: 8 edge slots (g=sub>>2), 4 lanes/edge, 8 ch/lane (uint4).
// Reduce masks 4/8/16 stay inside the half; head reduce 1/2 within 4 lanes.
__global__ __launch_bounds__(256) void gather2_kernel(const int* __restrict__ rowptr,
                                                      const int* __restrict__ csr_src,
                                                      const float* __restrict__ as2,
                                                      const float* __restrict__ ad2,
                                                      const unsigned* __restrict__ h2u,
                                                      const float* __restrict__ b2,
                                                      const float* __restrict__ Wh,
                                                      const float* __restrict__ bh,
                                                      const int* __restrict__ flags,
                                                      void* __restrict__ out, int n){
    const int wpair = blockIdx.x * 4 + (threadIdx.x >> 6);   // wave index: 2 nodes each
    const int lane  = threadIdx.x & 63;
    const int half  = lane >> 5;           // 0 or 1 -> which node
    const int sub   = lane & 31;
    const int wid   = wpair * 2 + half;
    if (wid >= n) return;                  // whole half exits together (wid uniform per half)
    const int g = sub >> 2;                // edge slot 0..7
    const int c = sub & 3;                 // channel quad (channels c*8..c*8+7)
    const int start = rowptr[wid], end = rowptr[wid + 1];
    const float adv = ad2[wid];
    float den = 0.f;
    float num[8] = {0.f,0.f,0.f,0.f,0.f,0.f,0.f,0.f};
    int j   = start + g;
    int src = (j < end) ? csr_src[j] : -1;
    const int iters = (end - start + 7) >> 3;
#pragma unroll 2
    for (int it = 0; it < iters; ++it){
        const int jn   = j + 8;
        const int srcn = (jn < end) ? csr_src[jn] : -1;   // prefetch next edge index
        if (src >= 0){
            uint4 hv = *(const uint4*)(h2u + (size_t)src * 16 + c * 4);
            float u = lrelu(as2[src] + adv);
            float w = __expf(u);
            den += w;
            num[0] += w * lo_bf(hv.x); num[1] += w * hi_bf(hv.x);
            num[2] += w * lo_bf(hv.y); num[3] += w * hi_bf(hv.y);
            num[4] += w * lo_bf(hv.z); num[5] += w * hi_bf(hv.z);
            num[6] += w * lo_bf(hv.w); num[7] += w * hi_bf(hv.w);
        }
        j = jn; src = srcn;
    }
    // reduce over edge-slot bits 2..4 (stays within the 32-lane half; preserves c)
    den += __shfl_xor(den, 4); den += __shfl_xor(den, 8); den += __shfl_xor(den, 16);
#pragma unroll
    for (int k = 0; k < 8; k++){
        num[k] += __shfl_xor(num[k], 4);
        num[k] += __shfl_xor(num[k], 8);
        num[k] += __shfl_xor(num[k], 16);
    }
    float p = 0.f;
    if (g == 0){                   // lanes sub 0..3 of each half hold the full sums
        const int ch0 = c * 8;
        float inv = 1.f / (den + 1e-16f);
#pragma unroll
        for (int k = 0; k < 8; k++){
            float v = num[k] * inv + b2[ch0 + k];
            v = v > 0.f ? v : __expf(v) - 1.f;
            p += v * Wh[ch0 + k];
        }
    }
    p += __shfl_xor(p, 1); p += __shfl_xor(p, 2);
    if (sub == 0){
        float r = p + bh[0];
        if (flags[1]) ((float*)out)[wid] = r;
        else          ((__hip_bfloat16*)out)[wid] = __float2bfloat16(r);
    }
}

extern "C" void kernel_launch(void* const* d_in, const int* in_sizes, int n_in,
                              void* d_out, int out_size, void* d_ws, size_t ws_size,
                              hipStream_t stream){
    const void* x   = d_in[0];
    const void* ei  = d_in[1];

    const int Nn = in_sizes[0] / 128;     // 100000
    const int Ee = in_sizes[1] / 2;       // 1600000
    const int Et = Ee + Nn;               // 1700000
    const int nsb = (Et + 4095) / 4096;   // scatter blocks

    char* ws = (char*)d_ws;
    auto al = [](size_t v){ return (v + 255) & ~(size_t)255; };
    size_t off = 0;
    int*      flags  = (int*)(ws + off);      off = al(off + 16);
    float*    wts    = (float*)(ws + off);    off = al(off + (size_t)WTS_TOTAL * 4);
    unsigned short* w1x = (unsigned short*)(ws + off); off = al(off + 160 * 128 * 2);
    unsigned short* w2x = (unsigned short*)(ws + off); off = al(off + 48 * 128 * 2);
    int*      gcur   = (int*)(ws + off);      off = al(off + (size_t)NBK * 4);
    int*      rowptr = (int*)(ws + off);      off = al(off + (size_t)(Nn + 1) * 4);
    int*      csrs   = (int*)(ws + off);      off = al(off + (size_t)Et * 4);
    unsigned* pairs  = (unsigned*)(ws + off); off = al(off + (size_t)NBK * BCAP * 4);
    size_t o_h1 = off;
    __hip_bfloat16* h1b = (__hip_bfloat16*)(ws + off); off = al(off + (size_t)Nn * 128 * 2);
    float* as1  = (float*)(ws + off); off = al(off + (size_t)Nn * 8 * 4);
    float* ad1  = (float*)(ws + off); off = al(off + (size_t)Nn * 8 * 4);
    unsigned* out1u = (unsigned*)(ws + off); off = al(off + (size_t)Nn * 128 * 2);
    // layer-2 buffers alias h1b region (dead after gather1)
    size_t o2 = o_h1;
    __hip_bfloat16* h2b = (__hip_bfloat16*)(ws + o2); o2 += (size_t)Nn * 32 * 2;
    float* as2  = (float*)(ws + o2);  o2 += (size_t)Nn * 4;
    float* ad2  = (float*)(ws + o2);  o2 += (size_t)Nn * 4;

    float* b1f  = wts + 20736;
    float* b2f  = wts + 20928;
    float* Whf  = wts + 20960;
    float* bhf  = wts + 20992;

    // 1) detect dtypes + init bucket cursors
    detect_kernel<<<1, 256, 0, stream>>>((const unsigned*)ei, (const unsigned*)x, flags, gcur);

    // 2) weight prep ∥ bucket scatter (block-specialized)
    prep_scatter_kernel<<<nsb + NPREP, 256, 0, stream>>>(ei, flags, gcur, pairs, Ee, Et, nsb,
        d_in[2], d_in[6], d_in[3], d_in[4], d_in[5], d_in[7], d_in[8], d_in[9],
        d_in[10], d_in[11], wts, w1x, w2x);

    // 3) per-bucket CSR build ∥ GEMM1+attn1 (block-specialized)
    g1csr_kernel<<<NBK + (Nn + 63) / 64, 256, 0, stream>>>(pairs, gcur, rowptr, csrs, Nn,
        x, w1x, flags, h1b, as1, ad1);

    // 4) gather layer 1
    gather1_kernel<<<(Nn + 3) / 4, 256, 0, stream>>>(rowptr, csrs, as1, ad1,
                                                     (const unsigned*)h1b, b1f, out1u, Nn);

    // 5) GEMM2 + attn2
    gemm2_kernel<<<(Nn + 63) / 64, 256, 0, stream>>>(out1u, w2x, h2b, as2, ad2, Nn);

    // 6) gather layer 2 + ordinal head — 2 nodes/wave, 8 nodes/block
    gather2_kernel<<<(Nn + 7) / 8, 256, 0, stream>>>(rowptr, csrs, as2, ad2,
                                                     (const unsigned*)h2b, b2f,
                                                     Whf, bhf, flags, d_out, Nn);
}

// Round 11
// 276.854 us; speedup vs baseline: 1.1124x; 1.0113x over previous
//
#include <hip/hip_runtime.h>
#include <hip/hip_bf16.h>
#include <stdint.h>
#include <stddef.h>

#define NEG_SLOPE 0.2f
#define XS 136   // padded LDS row stride in bf16 elems (272 B, 16B-aligned, kills 256B bank alias)

// CSR bucket build: bucket = dst >> 9 (512 nodes/bucket), 196 buckets for N=100k.
#define NBK   196
#define BWSH  9
#define BCAP  12288
#define NPREP 64   // prep blocks appended after scatter blocks

typedef __bf16 bf16x8 __attribute__((ext_vector_type(8)));
typedef float  f32x4  __attribute__((ext_vector_type(4)));

__device__ __forceinline__ float bf2f(__hip_bfloat16 b){ return __bfloat162float(b); }
__device__ __forceinline__ float lo_bf(unsigned u){ return __uint_as_float(u << 16); }
__device__ __forceinline__ float hi_bf(unsigned u){ return __uint_as_float(u & 0xffff0000u); }
__device__ __forceinline__ float lrelu(float u){ return fmaxf(u, NEG_SLOPE * u); }
__device__ __forceinline__ unsigned short f2bf(float f){           // RNE bf16
    unsigned u = __float_as_uint(f);
    return (unsigned short)((u + 0x7fffu + ((u >> 16) & 1u)) >> 16);
}
__device__ __forceinline__ float bfs2f(unsigned short s){ return __uint_as_float((unsigned)s << 16); }
__device__ __forceinline__ float ldraw(const void* p, int i, int isf){
    return isf ? ((const float*)p)[i] : bf2f(((const __hip_bfloat16*)p)[i]);
}

// ---------------------------------------------------------------- detect (1 block)
// flags[0]: 1 if edge_index is int64; flags[1]: 1 if floats are fp32. + gcur init.
__global__ void detect_kernel(const unsigned* __restrict__ ei,
                              const unsigned* __restrict__ xw,
                              int* __restrict__ flags,
                              int* __restrict__ gcur){
    __shared__ int vote;
    const int t = threadIdx.x;
    if (t == 0) vote = 0;
    if (t < NBK) gcur[t] = t * BCAP;
    __syncthreads();
    if (t < 64){
        unsigned long long m = __ballot(ei[2*t + 1] != 0u);
        if (t == 0) flags[0] = (m == 0ull) ? 1 : 0;
    }
    {
        unsigned lo = xw[t] & 0xffffu;
        unsigned e  = (lo >> 7) & 0xffu;
        int pl = ((lo & 0x7fffu) == 0u || (e >= 100u && e <= 140u)) ? 1 : 0;
        atomicAdd(&vote, pl);
    }
    __syncthreads();
    if (t == 0) flags[1] = (vote < 128) ? 1 : 0;
}

// ---------------------------------------------------------------- prep ∥ bucket scatter
// Blocks [0, nsb): register-resident bucket scatter of packed (src,dst) pairs.
// Blocks [nsb, nsb+NPREP): weight prep — all from RAW inputs, no internal deps:
//   wts tail (biases/attn vecs), W1^T/W2^T bf16, fused logit vectors (hi/lo).
//   w1x: rows 0-127 = W1^T; 128+h/136+h = va1s hi/lo; 144+h/152+h = va1d hi/lo
//   w2x: rows 0-31 = W2^T; 32/33 = va2s hi/lo; 34/35 = va2d hi/lo; 36-47 zero
#define WTS_TOTAL 20993
__global__ __launch_bounds__(256) void prep_scatter_kernel(
        const void* __restrict__ ei, const int* __restrict__ flags,
        int* __restrict__ gcur, unsigned* __restrict__ pairs, int E, int Et, int nsb,
        const void* W1, const void* W2, const void* a1s, const void* a1d,
        const void* b1, const void* a2s, const void* a2d, const void* b2,
        const void* Wh, const void* bh,
        float* __restrict__ w, unsigned short* __restrict__ w1x,
        unsigned short* __restrict__ w2x){
    const int t = threadIdx.x;
    if ((int)blockIdx.x < nsb){
        // ---------------- scatter ----------------
        __shared__ int cnt[NBK], base[NBK], lcnt[NBK];
        const int e0 = blockIdx.x * 4096;
        const int nE = min(4096, Et - e0);
        for (int i = t; i < NBK; i += 256){ cnt[i] = 0; lcnt[i] = 0; }
        __syncthreads();
        const int is64 = flags[0];
        int2 sd[16];
#pragma unroll
        for (int k = 0; k < 16; k++){
            int j = t + k * 256;
            if (j < nE){
                int e = e0 + j, s, d;
                if (e >= E){ s = e - E; d = s; }
                else if (is64){
                    const long long* p = (const long long*)ei;
                    s = (int)p[e]; d = (int)p[(size_t)E + e];
                } else {
                    const int* p = (const int*)ei;
                    s = p[e]; d = p[(size_t)E + e];
                }
                sd[k] = make_int2(s, d);
                atomicAdd(&cnt[d >> BWSH], 1);
            } else sd[k].y = -1;
        }
        __syncthreads();
        for (int b = t; b < NBK; b += 256)
            base[b] = cnt[b] ? atomicAdd(&gcur[b], cnt[b]) : 0;
        __syncthreads();
#pragma unroll
        for (int k = 0; k < 16; k++){
            if (sd[k].y >= 0){
                int b = sd[k].y >> BWSH;
                int r = atomicAdd(&lcnt[b], 1);
                pairs[(size_t)base[b] + r] = ((unsigned)sd[k].x << BWSH) | (unsigned)(sd[k].y & 511);
            }
        }
    } else {
        // ---------------- prep (grid-stride over NPREP blocks) ----------------
        const int p   = blockIdx.x - nsb;
        const int tid = p * 256 + t;
        const int NT  = NPREP * 256;
        const int isf = flags[1];
        // wts tail: indices 20480..20992 (attn vecs + biases), relative i in [0,513)
        for (int i = tid; i < 513; i += NT){
            int gi = 20480 + i;
            const void* src; int off;
            if      (gi < 20608){ src = a1s; off = gi - 20480; }
            else if (gi < 20736){ src = a1d; off = gi - 20608; }
            else if (gi < 20864){ src = b1;  off = gi - 20736; }
            else if (gi < 20896){ src = a2s; off = gi - 20864; }
            else if (gi < 20928){ src = a2d; off = gi - 20896; }
            else if (gi < 20960){ src = b2;  off = gi - 20928; }
            else if (gi < 20992){ src = Wh;  off = gi - 20960; }
            else                { src = bh;  off = 0; }
            w[gi] = ldraw(src, off, isf);
        }
        // W1^T bf16
        for (int i = tid; i < 16384; i += NT){
            int c = i >> 7, k = i & 127;
            w1x[i] = f2bf(ldraw(W1, k*128 + c, isf));
        }
        // W2^T bf16 + zero pad rows 36..47
        for (int i = tid; i < 4096; i += NT){
            int c = i >> 7, k = i & 127;
            w2x[i] = f2bf(ldraw(W2, k*32 + c, isf));
        }
        for (int i = tid; i < 12*128; i += NT) w2x[36*128 + i] = 0;
        // fused logit vectors layer 1 (from raw inputs)
        for (int i = tid; i < 1024; i += NT){          // i = h*128 + k
            int h = i >> 7, k = i & 127;
            float ss = 0.f, dd = 0.f;
#pragma unroll
            for (int j = 0; j < 16; j++){
                float hv = ldraw(W1, k*128 + h*16 + j, isf);
                ss += hv * ldraw(a1s, h*16 + j, isf);
                dd += hv * ldraw(a1d, h*16 + j, isf);
            }
            unsigned short sh = f2bf(ss), dh = f2bf(dd);
            w1x[(128+h)*128 + k] = sh;
            w1x[(136+h)*128 + k] = f2bf(ss - bfs2f(sh));
            w1x[(144+h)*128 + k] = dh;
            w1x[(152+h)*128 + k] = f2bf(dd - bfs2f(dh));
        }
        // fused logit vectors layer 2
        for (int k = tid; k < 128; k += NT){
            float ss = 0.f, dd = 0.f;
#pragma unroll
            for (int j = 0; j < 32; j++){
                float hv = ldraw(W2, k*32 + j, isf);
                ss += hv * ldraw(a2s, j, isf);
                dd += hv * ldraw(a2d, j, isf);
            }
            unsigned short sh = f2bf(ss), dh = f2bf(dd);
            w2x[32*128 + k] = sh;
            w2x[33*128 + k] = f2bf(ss - bfs2f(sh));
            w2x[34*128 + k] = dh;
            w2x[35*128 + k] = f2bf(dd - bfs2f(dh));
        }
    }
}

// ---------------------------------------------------------------- csr_build ∥ GEMM1
// Blocks [0, NBK): per-bucket CSR build. Blocks [NBK, NBK+gridGemm): MFMA GEMM1
// + fused attn1 logits. Shared-mem union (52224 B = gemm1's requirement).
__global__ __launch_bounds__(256) void g1csr_kernel(
        const unsigned* __restrict__ pairs, const int* __restrict__ gcur,
        int* __restrict__ rowptr, int* __restrict__ csr_src, int Nn,
        const void* __restrict__ xv, const unsigned short* __restrict__ w1x,
        const int* __restrict__ flags, __hip_bfloat16* __restrict__ h1b,
        float* __restrict__ as1, float* __restrict__ ad1){
    __shared__ __align__(16) char smem[52224];
    const int t = threadIdx.x;
    if ((int)blockIdx.x < NBK){
        // ---------------- csr_build ----------------
        int* ssz   = (int*)smem;           // 256
        int* sscan = ssz + 256;            // 256
        int* cnt   = sscan + 256;          // 512
        int* sh    = cnt + 512;            // 256
        const int b = blockIdx.x;
        int v = (t < NBK) ? (gcur[t] - t * BCAP) : 0;
        ssz[t] = v; sscan[t] = v;
        __syncthreads();
        for (int off = 1; off < 256; off <<= 1){
            int x = (t >= off) ? sscan[t - off] : 0;
            __syncthreads();
            sscan[t] += x;
            __syncthreads();
        }
        const int sz = ssz[b];
        const int eb = (b == 0) ? 0 : sscan[b - 1];
        if (b == 0 && t == 0) rowptr[Nn] = sscan[NBK - 1];
        const unsigned* pp = pairs + (size_t)b * BCAP;
        cnt[t] = 0; cnt[t + 256] = 0;
        __syncthreads();
        for (int i = t; i < sz; i += 256) atomicAdd(&cnt[pp[i] & 511u], 1);
        __syncthreads();
        int l0 = 2*t, l1 = 2*t + 1;
        int s0 = cnt[l0], s1 = cnt[l1], ts = s0 + s1;
        sh[t] = ts; __syncthreads();
        for (int off = 1; off < 256; off <<= 1){
            int x = (t >= off) ? sh[t - off] : 0;
            __syncthreads();
            sh[t] += x;
            __syncthreads();
        }
        int excl = sh[t] - ts;
        __syncthreads();
        cnt[l0] = eb + excl;
        cnt[l1] = eb + excl + s0;
        int n0 = (b << BWSH) + l0, n1 = (b << BWSH) + l1;
        if (n0 < Nn) rowptr[n0] = cnt[l0];
        if (n1 < Nn) rowptr[n1] = cnt[l1];
        __syncthreads();
        for (int i = t; i < sz; i += 256){
            unsigned sd = pp[i];
            int pos = atomicAdd(&cnt[sd & 511u], 1);
            csr_src[pos] = (int)(sd >> BWSH);
        }
    } else {
        // ---------------- gemm1 (MFMA) + attn1 ----------------
        __bf16* xls = (__bf16*)smem;                    // 64*XS = 17408 B
        __bf16* wls = (__bf16*)(smem + 64 * XS * 2);    // 128*XS = 34816 B
        const int row0 = ((int)blockIdx.x - NBK) * 64;
        const int n = Nn;

#pragma unroll
        for (int k = 0; k < 8; k++){
            int e = (t + k * 256) * 8;
            int c = e >> 7, kk = e & 127;
            *(uint4*)(&wls[c * XS + kk]) = *(const uint4*)(w1x + e);
        }
        if (row0 + 64 <= n){
            if (flags[1]){                              // fp32, float4 loads
                const float* xp = (const float*)xv + (size_t)row0 * 128;
#pragma unroll
                for (int k = 0; k < 8; k++){
                    int e = (t + k * 256) * 4;
                    int row = e >> 7, col = e & 127;
                    float4 vv = *(const float4*)(xp + e);
                    uint2 o;
                    o.x = (unsigned)f2bf(vv.x) | ((unsigned)f2bf(vv.y) << 16);
                    o.y = (unsigned)f2bf(vv.z) | ((unsigned)f2bf(vv.w) << 16);
                    *(uint2*)(&xls[row * XS + col]) = o;
                }
            } else {                                    // bf16, uint4 loads
                const unsigned short* xp = (const unsigned short*)xv + (size_t)row0 * 128;
#pragma unroll
                for (int k = 0; k < 4; k++){
                    int e = (t + k * 256) * 8;
                    int row = e >> 7, col = e & 127;
                    *(uint4*)(&xls[row * XS + col]) = *(const uint4*)(xp + e);
                }
            }
        } else {
            const int limit = (n - row0) * 128;
            if (flags[1]){
                const float* xp = (const float*)xv + (size_t)row0 * 128;
                for (int i = t; i < 64 * 128; i += 256){
                    float v = (i < limit) ? xp[i] : 0.f;
                    xls[(i >> 7) * XS + (i & 127)] = (__bf16)v;
                }
            } else {
                const unsigned short* xp = (const unsigned short*)xv + (size_t)row0 * 128;
                for (int i = t; i < 64 * 128; i += 256){
                    unsigned short v = (i < limit) ? xp[i] : (unsigned short)0;
                    ((unsigned short*)xls)[(i >> 7) * XS + (i & 127)] = v;
                }
            }
        }
        __syncthreads();

        const int w    = t >> 6;
        const int lane = t & 63;
        const int l15  = lane & 15;
        const int quad = lane >> 4;

        f32x4 acc[8] = {};
        f32x4 accS = {}, accD = {};
        const __bf16* xbase = &xls[(w * 16 + l15) * XS + quad * 8];
        const __bf16* wbase = &wls[l15 * XS + quad * 8];
        const unsigned short* vsrow = w1x + (128 + l15) * 128 + quad * 8;
        const unsigned short* vdrow = w1x + (144 + l15) * 128 + quad * 8;

#pragma unroll
        for (int ks = 0; ks < 4; ks++){
            bf16x8 af = *(const bf16x8*)(xbase + ks * 32);
#pragma unroll
            for (int tt = 0; tt < 8; tt++){
                bf16x8 bfr = *(const bf16x8*)(wbase + tt * 16 * XS + ks * 32);
                acc[tt] = __builtin_amdgcn_mfma_f32_16x16x32_bf16(af, bfr, acc[tt], 0, 0, 0);
            }
            bf16x8 bS = *(const bf16x8*)(vsrow + ks * 32);
            bf16x8 bD = *(const bf16x8*)(vdrow + ks * 32);
            accS = __builtin_amdgcn_mfma_f32_16x16x32_bf16(af, bS, accS, 0, 0, 0);
            accD = __builtin_amdgcn_mfma_f32_16x16x32_bf16(af, bD, accD, 0, 0, 0);
        }

#pragma unroll
        for (int tt = 0; tt < 8; tt++){
            int col = tt * 16 + l15;
#pragma unroll
            for (int r = 0; r < 4; r++){
                int row = row0 + w * 16 + quad * 4 + r;
                if (row < n) h1b[(size_t)row * 128 + col] = __float2bfloat16(acc[tt][r]);
            }
        }
#pragma unroll
        for (int r = 0; r < 4; r++){
            float vs = accS[r] + __shfl_xor(accS[r], 8);   // hi + lo
            float vd = accD[r] + __shfl_xor(accD[r], 8);
            int row = row0 + w * 16 + quad * 4 + r;
            if (l15 < 8 && row < n){
                as1[(size_t)row * 8 + l15] = vs;
                ad1[(size_t)row * 8 + l15] = vd;
            }
        }
    }
}

// ---------------------------------------------------------------- gather L1 (+bias+ELU)
// One wave per dst node: 8 edge slots (g=lane>>3), 8 lanes/edge, 16 ch/lane (2x uint4),
// next-edge csr_src prefetch. (Champion form — fabric-bound at 3.5 TB/s, unchanged.)
__global__ __launch_bounds__(256) void gather1_kernel(const int* __restrict__ rowptr,
                                                      const int* __restrict__ csr_src,
                                                      const float* __restrict__ as1,
                                                      const float* __restrict__ ad1,
                                                      const unsigned* __restrict__ h1u,
                                                      const float* __restrict__ b1,
                                                      unsigned* __restrict__ out1u, int n){
    int wid = blockIdx.x * 4 + (threadIdx.x >> 6);
    if (wid >= n) return;
    const int lane = threadIdx.x & 63;
    const int g    = lane >> 3;    // edge slot 0..7
    const int h    = lane & 7;     // head (= channel group h*16..h*16+15)
    const int start = rowptr[wid], end = rowptr[wid + 1];
    const float adv = ad1[(size_t)wid * 8 + h];
    float den = 0.f;
    float num[16] = {0.f,0.f,0.f,0.f,0.f,0.f,0.f,0.f,
                     0.f,0.f,0.f,0.f,0.f,0.f,0.f,0.f};
    int j   = start + g;
    int src = (j < end) ? csr_src[j] : -1;
    const int iters = (end - start + 7) >> 3;
#pragma unroll 2
    for (int it = 0; it < iters; ++it){
        const int jn   = j + 8;
        const int srcn = (jn < end) ? csr_src[jn] : -1;   // prefetch next edge index
        if (src >= 0){
            const unsigned* hp = h1u + (size_t)src * 64 + h * 8;
            uint4 hv0 = *(const uint4*)(hp);
            uint4 hv1 = *(const uint4*)(hp + 4);
            float u = lrelu(as1[src * 8 + h] + adv);
            float w = __expf(u);
            den += w;
            num[0]  += w * lo_bf(hv0.x); num[1]  += w * hi_bf(hv0.x);
            num[2]  += w * lo_bf(hv0.y); num[3]  += w * hi_bf(hv0.y);
            num[4]  += w * lo_bf(hv0.z); num[5]  += w * hi_bf(hv0.z);
            num[6]  += w * lo_bf(hv0.w); num[7]  += w * hi_bf(hv0.w);
            num[8]  += w * lo_bf(hv1.x); num[9]  += w * hi_bf(hv1.x);
            num[10] += w * lo_bf(hv1.y); num[11] += w * hi_bf(hv1.y);
            num[12] += w * lo_bf(hv1.z); num[13] += w * hi_bf(hv1.z);
            num[14] += w * lo_bf(hv1.w); num[15] += w * hi_bf(hv1.w);
        }
        j = jn; src = srcn;
    }
    // reduce over edge slots (lane bits 3,4,5) — preserves head h
    den += __shfl_xor(den, 8); den += __shfl_xor(den, 16); den += __shfl_xor(den, 32);
#pragma unroll
    for (int k = 0; k < 16; k++){
        num[k] += __shfl_xor(num[k], 8);
        num[k] += __shfl_xor(num[k], 16);
        num[k] += __shfl_xor(num[k], 32);
    }
    if (g == 0){                      // lanes 0..7: each writes 16 channels (32 B)
        const int ch0 = h * 16;
        float inv = 1.f / (den + 1e-16f);
        uint4 o0, o1;
        unsigned* op0 = (unsigned*)&o0;
        unsigned* op1 = (unsigned*)&o1;
#pragma unroll
        for (int m = 0; m < 4; m++){
            float r0 = num[2*m]   * inv + b1[ch0 + 2*m];
            float r1 = num[2*m+1] * inv + b1[ch0 + 2*m + 1];
            r0 = r0 > 0.f ? r0 : __expf(r0) - 1.f;
            r1 = r1 > 0.f ? r1 : __expf(r1) - 1.f;
            op0[m] = (unsigned)f2bf(r0) | ((unsigned)f2bf(r1) << 16);
        }
#pragma unroll
        for (int m = 4; m < 8; m++){
            float r0 = num[2*m]   * inv + b1[ch0 + 2*m];
            float r1 = num[2*m+1] * inv + b1[ch0 + 2*m + 1];
            r0 = r0 > 0.f ? r0 : __expf(r0) - 1.f;
            r1 = r1 > 0.f ? r1 : __expf(r1) - 1.f;
            op1[m - 4] = (unsigned)f2bf(r0) | ((unsigned)f2bf(r1) << 16);
        }
        unsigned* ob = out1u + (size_t)wid * 64 + h * 8;
        *(uint4*)(ob)     = o0;
        *(uint4*)(ob + 4) = o1;
    }
}

// ---------------------------------------------------------------- GEMM2 (MFMA) + attn2 fused
__global__ __launch_bounds__(256) void gemm2_kernel(const unsigned* __restrict__ out1u,
                                                    const unsigned short* __restrict__ w2x,
                                                    __hip_bfloat16* __restrict__ h2b,
                                                    float* __restrict__ as2,
                                                    float* __restrict__ ad2, int n){
    __shared__ __align__(16) __bf16 als[64 * XS];   // 17408 B
    __shared__ __align__(16) __bf16 wls[32 * XS];   // 8704 B
    const int t = threadIdx.x;
    const int row0 = blockIdx.x * 64;

#pragma unroll
    for (int k = 0; k < 2; k++){
        int e = (t + k * 256) * 8;
        int c = e >> 7, kk = e & 127;
        *(uint4*)(&wls[c * XS + kk]) = *(const uint4*)(w2x + e);
    }
    if (row0 + 64 <= n){
#pragma unroll
        for (int k = 0; k < 4; k++){
            int e = (t + k * 256) * 4;              // uint index
            int row = e >> 6, cu = e & 63;
            *(uint4*)(&((unsigned*)als)[row * 68 + cu]) =
                *(const uint4*)(out1u + (size_t)row0 * 64 + e);
        }
    } else {
        const int limit = (n - row0) * 64;
        for (int i = t; i < 64 * 64; i += 256){
            unsigned v = (i < limit) ? out1u[(size_t)row0 * 64 + i] : 0u;
            ((unsigned*)als)[(i >> 6) * 68 + (i & 63)] = v;
        }
    }
    __syncthreads();

    const int w    = t >> 6;
    const int lane = t & 63;
    const int l15  = lane & 15;
    const int quad = lane >> 4;

    f32x4 acc[2] = {};
    f32x4 accE = {};
    const __bf16* abase = &als[(w * 16 + l15) * XS + quad * 8];
    const __bf16* bbase = &wls[l15 * XS + quad * 8];
    const unsigned short* verow = w2x + (32 + l15) * 128 + quad * 8;

#pragma unroll
    for (int ks = 0; ks < 4; ks++){
        bf16x8 af = *(const bf16x8*)(abase + ks * 32);
#pragma unroll
        for (int tt = 0; tt < 2; tt++){
            bf16x8 bfr = *(const bf16x8*)(bbase + tt * 16 * XS + ks * 32);
            acc[tt] = __builtin_amdgcn_mfma_f32_16x16x32_bf16(af, bfr, acc[tt], 0, 0, 0);
        }
        bf16x8 bE = *(const bf16x8*)(verow + ks * 32);
        accE = __builtin_amdgcn_mfma_f32_16x16x32_bf16(af, bE, accE, 0, 0, 0);
    }

#pragma unroll
    for (int r = 0; r < 4; r++){
        int row = row0 + w * 16 + quad * 4 + r;
        if (row < n){
#pragma unroll
            for (int tt = 0; tt < 2; tt++){
                int col = tt * 16 + l15;
                h2b[(size_t)row * 32 + col] = __float2bfloat16(acc[tt][r]);
            }
        }
        float vE = accE[r] + __shfl_xor(accE[r], 1);  // hi + lo
        if (row < n){
            if (l15 == 0) as2[row] = vE;              // cols 32+33
            if (l15 == 2) ad2[row] = vE;              // cols 34+35
        }
    }
}

// ---------------------------------------------------------------- gather L2 + head (fused)
// FOUR nodes per wave: 16 lanes/node (quarter q=lane>>4), 4 edge slots (g=sub>>2),
// 4 lanes/edge, 8 ch/lane (uint4). Reduce masks 4/8 stay inside the quarter;
// head reduce 1/2 within 4 lanes. Waves: 100k -> 25k (per-node shfl 13.5 -> 4.5).
__global__ __launch_bounds__(256) void gather2_kernel(const int* __restrict__ rowptr,
                                                      const int* __restrict__ csr_src,
                                                      const float* __restrict__ as2,
                                                      const float* __restrict__ ad2,
                                                      const unsigned* __restrict__ h2u,
                                                      const float* __restrict__ b2,
                                                      const float* __restrict__ Wh,
                                                      const float* __restrict__ bh,
                                                      const int* __restrict__ flags,
                                                      void* __restrict__ out, int n){
    const int wq   = blockIdx.x * 4 + (threadIdx.x >> 6);   // wave index: 4 nodes each
    const int lane = threadIdx.x & 63;
    const int q    = lane >> 4;            // quarter 0..3 -> which node
    const int sub  = lane & 15;
    const int wid  = wq * 4 + q;
    if (wid >= n) return;                  // whole quarter exits together (wid uniform/quarter)
    const int g = sub >> 2;                // edge slot 0..3
    const int c = sub & 3;                 // channel quad (channels c*8..c*8+7)
    const int start = rowptr[wid], end = rowptr[wid + 1];
    const float adv = ad2[wid];
    float den = 0.f;
    float num[8] = {0.f,0.f,0.f,0.f,0.f,0.f,0.f,0.f};
    int j   = start + g;
    int src = (j < end) ? csr_src[j] : -1;
    const int iters = (end - start + 3) >> 2;
#pragma unroll 2
    for (int it = 0; it < iters; ++it){
        const int jn   = j + 4;
        const int srcn = (jn < end) ? csr_src[jn] : -1;   // prefetch next edge index
        if (src >= 0){
            uint4 hv = *(const uint4*)(h2u + (size_t)src * 16 + c * 4);
            float u = lrelu(as2[src] + adv);
            float w = __expf(u);
            den += w;
            num[0] += w * lo_bf(hv.x); num[1] += w * hi_bf(hv.x);
            num[2] += w * lo_bf(hv.y); num[3] += w * hi_bf(hv.y);
            num[4] += w * lo_bf(hv.z); num[5] += w * hi_bf(hv.z);
            num[6] += w * lo_bf(hv.w); num[7] += w * hi_bf(hv.w);
        }
        j = jn; src = srcn;
    }
    // reduce over edge-slot bits 2..3 (stays within the 16-lane quarter; preserves c)
    den += __shfl_xor(den, 4); den += __shfl_xor(den, 8);
#pragma unroll
    for (int k = 0; k < 8; k++){
        num[k] += __shfl_xor(num[k], 4);
        num[k] += __shfl_xor(num[k], 8);
    }
    float p = 0.f;
    if (g == 0){                   // lanes sub 0..3 of each quarter hold the full sums
        const int ch0 = c * 8;
        float inv = 1.f / (den + 1e-16f);
#pragma unroll
        for (int k = 0; k < 8; k++){
            float v = num[k] * inv + b2[ch0 + k];
            v = v > 0.f ? v : __expf(v) - 1.f;
            p += v * Wh[ch0 + k];
        }
    }
    p += __shfl_xor(p, 1); p += __shfl_xor(p, 2);
    if (sub == 0){
        float r = p + bh[0];
        if (flags[1]) ((float*)out)[wid] = r;
        else          ((__hip_bfloat16*)out)[wid] = __float2bfloat16(r);
    }
}

extern "C" void kernel_launch(void* const* d_in, const int* in_sizes, int n_in,
                              void* d_out, int out_size, void* d_ws, size_t ws_size,
                              hipStream_t stream){
    const void* x   = d_in[0];
    const void* ei  = d_in[1];

    const int Nn = in_sizes[0] / 128;     // 100000
    const int Ee = in_sizes[1] / 2;       // 1600000
    const int Et = Ee + Nn;               // 1700000
    const int nsb = (Et + 4095) / 4096;   // scatter blocks

    char* ws = (char*)d_ws;
    auto al = [](size_t v){ return (v + 255) & ~(size_t)255; };
    size_t off = 0;
    int*      flags  = (int*)(ws + off);      off = al(off + 16);
    float*    wts    = (float*)(ws + off);    off = al(off + (size_t)WTS_TOTAL * 4);
    unsigned short* w1x = (unsigned short*)(ws + off); off = al(off + 160 * 128 * 2);
    unsigned short* w2x = (unsigned short*)(ws + off); off = al(off + 48 * 128 * 2);
    int*      gcur   = (int*)(ws + off);      off = al(off + (size_t)NBK * 4);
    int*      rowptr = (int*)(ws + off);      off = al(off + (size_t)(Nn + 1) * 4);
    int*      csrs   = (int*)(ws + off);      off = al(off + (size_t)Et * 4);
    unsigned* pairs  = (unsigned*)(ws + off); off = al(off + (size_t)NBK * BCAP * 4);
    size_t o_h1 = off;
    __hip_bfloat16* h1b = (__hip_bfloat16*)(ws + off); off = al(off + (size_t)Nn * 128 * 2);
    float* as1  = (float*)(ws + off); off = al(off + (size_t)Nn * 8 * 4);
    float* ad1  = (float*)(ws + off); off = al(off + (size_t)Nn * 8 * 4);
    unsigned* out1u = (unsigned*)(ws + off); off = al(off + (size_t)Nn * 128 * 2);
    // layer-2 buffers alias h1b region (dead after gather1)
    size_t o2 = o_h1;
    __hip_bfloat16* h2b = (__hip_bfloat16*)(ws + o2); o2 += (size_t)Nn * 32 * 2;
    float* as2  = (float*)(ws + o2);  o2 += (size_t)Nn * 4;
    float* ad2  = (float*)(ws + o2);  o2 += (size_t)Nn * 4;

    float* b1f  = wts + 20736;
    float* b2f  = wts + 20928;
    float* Whf  = wts + 20960;
    float* bhf  = wts + 20992;

    // 1) detect dtypes + init bucket cursors
    detect_kernel<<<1, 256, 0, stream>>>((const unsigned*)ei, (const unsigned*)x, flags, gcur);

    // 2) weight prep ∥ bucket scatter (block-specialized)
    prep_scatter_kernel<<<nsb + NPREP, 256, 0, stream>>>(ei, flags, gcur, pairs, Ee, Et, nsb,
        d_in[2], d_in[6], d_in[3], d_in[4], d_in[5], d_in[7], d_in[8], d_in[9],
        d_in[10], d_in[11], wts, w1x, w2x);

    // 3) per-bucket CSR build ∥ GEMM1+attn1 (block-specialized)
    g1csr_kernel<<<NBK + (Nn + 63) / 64, 256, 0, stream>>>(pairs, gcur, rowptr, csrs, Nn,
        x, w1x, flags, h1b, as1, ad1);

    // 4) gather layer 1
    gather1_kernel<<<(Nn + 3) / 4, 256, 0, stream>>>(rowptr, csrs, as1, ad1,
                                                     (const unsigned*)h1b, b1f, out1u, Nn);

    // 5) GEMM2 + attn2
    gemm2_kernel<<<(Nn + 63) / 64, 256, 0, stream>>>(out1u, w2x, h2b, as2, ad2, Nn);

    // 6) gather layer 2 + ordinal head — 4 nodes/wave, 16 nodes/block
    gather2_kernel<<<(Nn + 15) / 16, 256, 0, stream>>>(rowptr, csrs, as2, ad2,
                                                       (const unsigned*)h2b, b2f,
                                                       Whf, bhf, flags, d_out, Nn);
}